// Round 1
// baseline (334.514 us; speedup 1.0000x reference)
//
#include <hip/hip_runtime.h>

#define BB 8
#define CC 3
#define HH 512
#define WW 512
#define KT 5   // kernel taps per dim

// fast tanh: tanh(v) = (e^{2v}-1)/(e^{2v}+1), clamp to avoid inf/inf
__device__ __forceinline__ float fast_tanh(float v) {
    v = fminf(15.0f, fmaxf(-15.0f, v));
    float t = __expf(2.0f * v);
    return __fdividef(t - 1.0f, t + 1.0f);
}

// Each thread: pixel block rows {h0, h0+1}, cols {w0..w0+3}, all 3 channels.
// 24 result outputs + 6 pooled outputs, pool is thread-local.
__global__ __launch_bounds__(256) void FilterNetworkDownsample_kernel(
    const float* __restrict__ x,        // (B, C, H, W)
    const float* __restrict__ kp,       // (B, 25, H, W)
    float* __restrict__ result,         // (B, C, H, W)
    float* __restrict__ down)           // (B, C, H/2, W/2)
{
    const int gid  = blockIdx.x * blockDim.x + threadIdx.x;
    const int wi   = gid & 127;          // W/4 = 128 threads across width
    const int rest = gid >> 7;
    const int hb   = rest & 255;         // H/2 = 256 row-pairs
    const int b    = rest >> 8;
    const int w0   = wi << 2;
    const int h0   = hb << 1;

    float acc[2][CC][4];
#pragma unroll
    for (int r = 0; r < 2; ++r)
#pragma unroll
        for (int c = 0; c < CC; ++c)
#pragma unroll
            for (int p = 0; p < 4; ++p) acc[r][c][p] = 0.0f;

    const float* xb = x  + (size_t)b * CC * HH * WW;
    const float* kb = kp + (size_t)b * (KT * KT) * HH * WW;

    // Loop over the 6 distinct x rows this 2-row output block touches.
#pragma unroll
    for (int l = 0; l < 6; ++l) {
        const int row = h0 - 2 + l;
        const bool rowok = (row >= 0) && (row < HH);

        // xr[c][q] = x[b, c, row, w0-4+q], q in 0..11 (zero outside image)
        float xr[CC][12];
#pragma unroll
        for (int c = 0; c < CC; ++c) {
            const float* xrow = xb + ((size_t)c * HH + (size_t)row) * WW;
            float4 f0, f1, f2;
            if (rowok && w0 > 0)       f0 = *reinterpret_cast<const float4*>(xrow + w0 - 4);
            else                       f0 = make_float4(0.f, 0.f, 0.f, 0.f);
            if (rowok)                 f1 = *reinterpret_cast<const float4*>(xrow + w0);
            else                       f1 = make_float4(0.f, 0.f, 0.f, 0.f);
            if (rowok && w0 < WW - 4)  f2 = *reinterpret_cast<const float4*>(xrow + w0 + 4);
            else                       f2 = make_float4(0.f, 0.f, 0.f, 0.f);
            xr[c][0] = f0.x; xr[c][1] = f0.y; xr[c][2]  = f0.z; xr[c][3]  = f0.w;
            xr[c][4] = f1.x; xr[c][5] = f1.y; xr[c][6]  = f1.z; xr[c][7]  = f1.w;
            xr[c][8] = f2.x; xr[c][9] = f2.y; xr[c][10] = f2.z; xr[c][11] = f2.w;
        }

        // This x row feeds output row r=0 as tap i=l, and r=1 as tap i=l-1.
#pragma unroll
        for (int r = 0; r < 2; ++r) {
            const int i = l - r;
            if (i < 0 || i >= KT) continue;
            const int hrow = h0 + r;

            float th[KT][4];
#pragma unroll
            for (int j = 0; j < KT; ++j) {
                const int k = i * KT + j;
                const float4 wv = *reinterpret_cast<const float4*>(
                    kb + ((size_t)k * HH + (size_t)hrow) * WW + w0);
                th[j][0] = fast_tanh(wv.x);
                th[j][1] = fast_tanh(wv.y);
                th[j][2] = fast_tanh(wv.z);
                th[j][3] = fast_tanh(wv.w);
            }

#pragma unroll
            for (int c = 0; c < CC; ++c)
#pragma unroll
                for (int j = 0; j < KT; ++j)
#pragma unroll
                    for (int p = 0; p < 4; ++p)
                        acc[r][c][p] = fmaf(xr[c][p + j + 2], th[j][p], acc[r][c][p]);
        }
    }

    // Write result (coalesced float4 per row/channel)
#pragma unroll
    for (int r = 0; r < 2; ++r)
#pragma unroll
        for (int c = 0; c < CC; ++c) {
            float4 o = make_float4(acc[r][c][0], acc[r][c][1], acc[r][c][2], acc[r][c][3]);
            *reinterpret_cast<float4*>(
                result + ((size_t)(b * CC + c) * HH + (size_t)(h0 + r)) * WW + w0) = o;
        }

    // Write downsample (coalesced float2 per channel)
#pragma unroll
    for (int c = 0; c < CC; ++c) {
        float2 d;
        d.x = (acc[0][c][0] + acc[0][c][1] + acc[1][c][0] + acc[1][c][1]) * 0.25f;
        d.y = (acc[0][c][2] + acc[0][c][3] + acc[1][c][2] + acc[1][c][3]) * 0.25f;
        *reinterpret_cast<float2*>(
            down + ((size_t)(b * CC + c) * (HH / 2) + (size_t)hb) * (WW / 2) + (w0 >> 1)) = d;
    }
}

extern "C" void kernel_launch(void* const* d_in, const int* in_sizes, int n_in,
                              void* d_out, int out_size, void* d_ws, size_t ws_size,
                              hipStream_t stream) {
    const float* x  = (const float*)d_in[0];
    const float* kp = (const float*)d_in[1];
    float* result = (float*)d_out;                       // B*C*H*W = 6291456 floats
    float* down   = (float*)d_out + (size_t)BB * CC * HH * WW;  // B*C*(H/2)*(W/2)

    const int threads = BB * (HH / 2) * (WW / 4);        // 262144
    const int block = 256;
    const int grid = threads / block;                    // 1024
    FilterNetworkDownsample_kernel<<<grid, block, 0, stream>>>(x, kp, result, down);
}